// Round 3
// baseline (167.767 us; speedup 1.0000x reference)
//
#include <hip/hip_runtime.h>
#include <hip/hip_bf16.h>

#define FEAT 256
#define HEADS 8
#define HD 32
#define POSN 128
#define NEGN 128
#define HWN 16384
#define BN 8
#define NSLOT 512
#define S_TOT 256
#define LN_EPS 1e-5f
#define NBKT 4096
#define AFF_OFF (NSLOT*FEAT)   /* 131072 floats: new_slots first, then affinities */

typedef float f32x4 __attribute__((ext_vector_type(4)));

__device__ __forceinline__ f32x4 ntload4(const float* p) {
    return __builtin_nontemporal_load((const f32x4*)p);
}

// ---------------- K1: exact feat_idx sampling + folded qkw -------------------
__global__ __launch_bounds__(256) void k_sample_qkw(const float* __restrict__ curio,
                                                    const int* __restrict__ mme_p,
                                                    const float* __restrict__ slots,
                                                    const float* __restrict__ ipw,
                                                    const float* __restrict__ ipb,
                                                    int* __restrict__ fi_t,
                                                    float* __restrict__ qkw,
                                                    float* __restrict__ qkb)
{
    __shared__ uint32_t hist[NBKT];    // 16KB
    __shared__ uint16_t offs[NBKT];    // 8KB
    __shared__ uint16_t sidx[HWN];     // 32KB
    __shared__ uint32_t ssum[256];     // 1KB
    __shared__ float srow[FEAT];
    __shared__ float qrow[FEAT];
    int slot = blockIdx.x, t = threadIdx.x;
    const float* cm = curio + (size_t)slot * HWN;

    for (int i = t; i < NBKT; i += 256) hist[i] = 0;
    __syncthreads();
    for (int i = t; i < HWN; i += 256) {
        float v = cm[i];
        int b = (int)(v * 4096.0f);
        b = b < 0 ? 0 : (b > NBKT-1 ? NBKT-1 : b);
        atomicAdd(&hist[b], 1u);
    }
    __syncthreads();
    uint32_t lsum = 0;
    int base = t * 16;
    for (int j = 0; j < 16; j++) lsum += hist[NBKT-1 - (base + j)];
    ssum[t] = lsum; __syncthreads();
    for (int off = 1; off < 256; off <<= 1) {
        uint32_t v = (t >= off) ? ssum[t - off] : 0u;
        __syncthreads();
        ssum[t] += v;
        __syncthreads();
    }
    uint32_t run = ssum[t] - lsum;
    for (int j = 0; j < 16; j++) {
        int b = NBKT-1 - (base + j);
        offs[b] = (uint16_t)run;
        run += hist[b];
    }
    __syncthreads();
    for (int i = t; i < NBKT; i += 256) hist[i] = 0;
    __syncthreads();
    for (int i = t; i < HWN; i += 256) {
        float v = cm[i];
        int b = (int)(v * 4096.0f);
        b = b < 0 ? 0 : (b > NBKT-1 ? NBKT-1 : b);
        uint32_t pos = (uint32_t)offs[b] + atomicAdd(&hist[b], 1u);
        sidx[pos] = (uint16_t)i;
    }
    __syncthreads();

    int mme = mme_p[0];
    int stride = (HWN - POSN - mme) / NEGN;          // 127 for mme=0
    int r = (t < POSN) ? t : (POSN + stride * (t - POSN));
    int lo = 0, hi = NBKT - 1;
    while (lo < hi) { int mid = (lo + hi) >> 1; if ((int)offs[mid] <= r) hi = mid; else lo = mid + 1; }
    int bkt = lo;
    int start = (int)offs[bkt];
    int cnt   = (int)hist[bkt];
    int rr = r - start;
    int besti = sidx[start + (rr < cnt ? rr : 0)];
    for (int j = 0; j < cnt; j++) {
        int ij = sidx[start + j];
        float vj = cm[ij];
        int rank = 0;
        for (int j2 = 0; j2 < cnt; j2++) {
            int i2 = sidx[start + j2];
            float v2 = cm[i2];
            if (v2 > vj || (v2 == vj && i2 < ij)) rank++;
        }
        if (rank == rr) { besti = ij; break; }
    }
    fi_t[slot * S_TOT + t] = besti;   // fi_t[n][s]

    // ---- folded qkw for this slot ----
    __syncthreads();
    srow[t] = slots[slot * FEAT + t];
    __syncthreads();
    {
        const float* qwrow = ipw + (size_t)t * FEAT;
        float acc = 0.f;
#pragma unroll 8
        for (int f = 0; f < FEAT; f++) acc += srow[f] * qwrow[f];
        const float scaling = 0.17677669529663687f;     // 32^-0.5
        qrow[t] = (acc + ipb[t]) * scaling;
    }
    __syncthreads();
    if (t < HEADS) {
        float s = 0.f;
        for (int d = 0; d < HD; d++) s += qrow[t*HD + d] * ipb[FEAT + t*HD + d];
        qkb[slot * HEADS + t] = s;
    }
    const float* kw = ipw + FEAT * FEAT;
    for (int e = t; e < HEADS * FEAT; e += 256) {
        int h = e >> 8, f = e & 255;
        float s = 0.f;
#pragma unroll
        for (int d = 0; d < HD; d++) s += qrow[h*HD + d] * kw[(h*HD + d) * FEAT + f];
        qkw[(size_t)slot * (HEADS*FEAT) + e] = s;
    }
}

// ---------------- K2: fused affinity + softmax + output ---------------------
// One block per slot, 512 threads (8 waves). Wave w gathers rows p = w + 8*i,
// i=0..31 (feat+pos, nontemporal), computes affinities in registers with a
// 64-lane value-halving butterfly. POS rows (i<16) also keep their feat
// float4 in registers (cache[16], 64 VGPR). Then softmax, register-cached
// weighted-feature sum, V-proj, out-proj, residual+LN — no second gather.
__global__ __launch_bounds__(512, 2) void k_attn(const float* __restrict__ features,
                                                 const float* __restrict__ pos_enc,
                                                 const int* __restrict__ batch_idx,
                                                 const int* __restrict__ fi_t,
                                                 const float* __restrict__ qkw,
                                                 const float* __restrict__ qkb,
                                                 const float* __restrict__ slots,
                                                 const float* __restrict__ ipw,
                                                 const float* __restrict__ ipb,
                                                 const float* __restrict__ out_w,
                                                 const float* __restrict__ out_b,
                                                 const float* __restrict__ ln_g,
                                                 const float* __restrict__ ln_b,
                                                 float* __restrict__ aff_out,
                                                 float* __restrict__ out)
{
    __shared__ int   fi_l[S_TOT];                      // 1KB
    __shared__ float qkb_l[HEADS];
    __shared__ __align__(16) float affP[POSN][8];      // 4KB: aff then attn
    __shared__ f32x4 wfp[8][HEADS][64];                // 64KB per-wave partials
    __shared__ f32x4 wf4[HEADS][64];                   // 8KB combined
    __shared__ float aoh[512];                         // 2KB
    __shared__ __align__(16) float ao_l[FEAT];         // 1KB
    __shared__ float xgh[512];                         // 2KB
    __shared__ float r1[4], r2[4];

    int n = blockIdx.x, t = threadIdx.x, lane = t & 63, w = t >> 6;
    if (t < S_TOT) fi_l[t] = fi_t[n * S_TOT + t];
    if (t < HEADS) qkb_l[t] = qkb[n * HEADS + t];
    int b = batch_idx[n];

    const float* qk = qkw + (size_t)n * (HEADS*FEAT) + 4 * lane;
    f32x4 qw0 = *(const f32x4*)(qk + 0*FEAT);
    f32x4 qw1 = *(const f32x4*)(qk + 1*FEAT);
    f32x4 qw2 = *(const f32x4*)(qk + 2*FEAT);
    f32x4 qw3 = *(const f32x4*)(qk + 3*FEAT);
    f32x4 qw4 = *(const f32x4*)(qk + 4*FEAT);
    f32x4 qw5 = *(const f32x4*)(qk + 5*FEAT);
    f32x4 qw6 = *(const f32x4*)(qk + 6*FEAT);
    f32x4 qw7 = *(const f32x4*)(qk + 7*FEAT);
    __syncthreads();
    float qb = qkb_l[lane & 7];
    int b0 = lane & 1, b1 = (lane >> 1) & 1, b2 = (lane >> 2) & 1;

    auto dorow = [&](int p, f32x4 cf, f32x4 cg) {
        float x0 = cf[0]+cg[0], x1 = cf[1]+cg[1], x2 = cf[2]+cg[2], x3 = cf[3]+cg[3];
        float p0 = x0*qw0[0] + x1*qw0[1] + x2*qw0[2] + x3*qw0[3];
        float p1 = x0*qw1[0] + x1*qw1[1] + x2*qw1[2] + x3*qw1[3];
        float p2 = x0*qw2[0] + x1*qw2[1] + x2*qw2[2] + x3*qw2[3];
        float p3 = x0*qw3[0] + x1*qw3[1] + x2*qw3[2] + x3*qw3[3];
        float p4 = x0*qw4[0] + x1*qw4[1] + x2*qw4[2] + x3*qw4[3];
        float p5 = x0*qw5[0] + x1*qw5[1] + x2*qw5[2] + x3*qw5[3];
        float p6 = x0*qw6[0] + x1*qw6[1] + x2*qw6[2] + x3*qw6[3];
        float p7 = x0*qw7[0] + x1*qw7[1] + x2*qw7[2] + x3*qw7[3];
        float s0 = b0 ? p0 : p1, s1 = b0 ? p2 : p3, s2 = b0 ? p4 : p5, s3 = b0 ? p6 : p7;
        float a0 = (b0 ? p1 : p0) + __shfl_xor(s0, 1);
        float a1 = (b0 ? p3 : p2) + __shfl_xor(s1, 1);
        float a2 = (b0 ? p5 : p4) + __shfl_xor(s2, 1);
        float a3 = (b0 ? p7 : p6) + __shfl_xor(s3, 1);
        float u0 = b1 ? a0 : a1, u1 = b1 ? a2 : a3;
        float c0 = (b1 ? a1 : a0) + __shfl_xor(u0, 2);
        float c1 = (b1 ? a3 : a2) + __shfl_xor(u1, 2);
        float u2 = b2 ? c0 : c1;
        float d = (b2 ? c1 : c0) + __shfl_xor(u2, 4);
        d += __shfl_xor(d, 8);
        d += __shfl_xor(d, 16);
        d += __shfl_xor(d, 32);
        d += qb;
        if (lane < 8) {
            aff_out[(size_t)p * (NSLOT*HEADS) + n*HEADS + lane] = d;
            if (p < POSN) affP[p][lane] = d;
        }
    };

    f32x4 cache[16];
    size_t base0 = ((size_t)fi_l[w] * BN + b) * FEAT + 4 * lane;
    f32x4 f4 = ntload4(features + base0);
    f32x4 g4 = ntload4(pos_enc + base0);
#pragma unroll
    for (int i = 0; i < 16; i++) {
        f32x4 cf = f4, cg = g4;
        {
            size_t nb = ((size_t)fi_l[w + 8*(i+1)] * BN + b) * FEAT + 4 * lane;
            f4 = ntload4(features + nb);
            g4 = ntload4(pos_enc + nb);
        }
        cache[i] = cf;
        dorow(w + 8*i, cf, cg);
    }
#pragma unroll 4
    for (int i = 16; i < 32; i++) {
        f32x4 cf = f4, cg = g4;
        if (i < 31) {
            size_t nb = ((size_t)fi_l[w + 8*(i+1)] * BN + b) * FEAT + 4 * lane;
            f4 = ntload4(features + nb);
            g4 = ntload4(pos_enc + nb);
        }
        dorow(w + 8*i, cf, cg);
    }
    __syncthreads();

    // softmax over p<128 per head (t<256: wave-local 32-lane groups)
    if (t < 256) {
        int h = t >> 5, l = t & 31;
        float v0 = affP[l][h], v1 = affP[l+32][h], v2 = affP[l+64][h], v3 = affP[l+96][h];
        float m = fmaxf(fmaxf(v0, v1), fmaxf(v2, v3));
        for (int off = 16; off > 0; off >>= 1) m = fmaxf(m, __shfl_xor(m, off, 32));
        float e0 = expf(v0 - m), e1 = expf(v1 - m), e2 = expf(v2 - m), e3 = expf(v3 - m);
        float s = e0 + e1 + e2 + e3;
        for (int off = 16; off > 0; off >>= 1) s += __shfl_xor(s, off, 32);
        float inv = 1.0f / s;
        affP[l][h] = e0*inv; affP[l+32][h] = e1*inv; affP[l+64][h] = e2*inv; affP[l+96][h] = e3*inv;
    }
    __syncthreads();

    // weighted feature sum from register cache: acc[h][quad] per wave
    {
        f32x4 acc[8];
#pragma unroll
        for (int h = 0; h < 8; h++) acc[h] = (f32x4){0.f,0.f,0.f,0.f};
#pragma unroll
        for (int i = 0; i < 16; i++) {
            int p = w + 8*i;
            const f32x4* ap = (const f32x4*)&affP[p][0];
            f32x4 a03 = ap[0], a47 = ap[1];
            acc[0] += cache[i] * a03[0];
            acc[1] += cache[i] * a03[1];
            acc[2] += cache[i] * a03[2];
            acc[3] += cache[i] * a03[3];
            acc[4] += cache[i] * a47[0];
            acc[5] += cache[i] * a47[1];
            acc[6] += cache[i] * a47[2];
            acc[7] += cache[i] * a47[3];
        }
#pragma unroll
        for (int h = 0; h < 8; h++) wfp[w][h][lane] = acc[h];
    }
    __syncthreads();
    {   // combine 8 wave partials (HEADS*64 = 512 elements, one per thread)
        int h = t >> 6, q2 = t & 63;
        f32x4 s = wfp[0][h][q2];
#pragma unroll
        for (int ww = 1; ww < 8; ww++) s += wfp[ww][h][q2];
        wf4[h][q2] = s;
    }
    __syncthreads();

    // V-projection split in half across 512 threads
    {
        int g = t & 255, half = t >> 8;
        const float* vwrow = ipw + (size_t)(2*FEAT + g) * FEAT + half*128;
        const f32x4* wfv = &wf4[g >> 5][half*32];
        float s = 0.f;
#pragma unroll 8
        for (int f4i = 0; f4i < 32; f4i++) {
            f32x4 wv = *(const f32x4*)(vwrow + 4*f4i);
            f32x4 y = wfv[f4i];
            s += wv[0]*y[0] + wv[1]*y[1] + wv[2]*y[2] + wv[3]*y[3];
        }
        aoh[t] = s;
    }
    __syncthreads();
    if (t < 256) ao_l[t] = aoh[t] + aoh[t + 256] + ipb[2*FEAT + t];
    __syncthreads();

    // out-projection split in half
    {
        int g = t & 255, half = t >> 8;
        const float* owrow = out_w + (size_t)g * FEAT + half*128;
        const f32x4* av = (const f32x4*)&ao_l[half*128];
        float s = 0.f;
#pragma unroll 8
        for (int f4i = 0; f4i < 32; f4i++) {
            f32x4 wv = *(const f32x4*)(owrow + 4*f4i);
            f32x4 y = av[f4i];
            s += wv[0]*y[0] + wv[1]*y[1] + wv[2]*y[2] + wv[3]*y[3];
        }
        xgh[t] = s;
    }
    __syncthreads();

    float xg = 0.f;
    if (t < 256) {
        xg = xgh[t] + xgh[t + 256] + out_b[t] + slots[n * FEAT + t];
        float s1 = xg, s2 = xg * xg;
        for (int off = 32; off > 0; off >>= 1) {
            s1 += __shfl_xor(s1, off);
            s2 += __shfl_xor(s2, off);
        }
        if ((t & 63) == 0) { r1[t >> 6] = s1; r2[t >> 6] = s2; }
    }
    __syncthreads();
    if (t < 256) {
        float sum1 = r1[0] + r1[1] + r1[2] + r1[3];
        float sum2 = r2[0] + r2[1] + r2[2] + r2[3];
        float mu  = sum1 * (1.0f / FEAT);
        float var = sum2 * (1.0f / FEAT) - mu * mu;
        float nrm = (xg - mu) * rsqrtf(var + LN_EPS);
        out[n * FEAT + t] = nrm * ln_g[t] + ln_b[t];
    }
}

extern "C" void kernel_launch(void* const* d_in, const int* in_sizes, int n_in,
                              void* d_out, int out_size, void* d_ws, size_t ws_size,
                              hipStream_t stream)
{
    (void)in_sizes; (void)n_in; (void)out_size; (void)ws_size;
    const float* slots    = (const float*)d_in[0];
    const float* features = (const float*)d_in[1];
    const float* pos_enc  = (const float*)d_in[2];
    const float* curio    = (const float*)d_in[3];
    const int*   batch_idx= (const int*)d_in[4];
    const float* ipw      = (const float*)d_in[5];
    const float* ipb      = (const float*)d_in[6];
    const float* out_w    = (const float*)d_in[7];
    const float* out_b    = (const float*)d_in[8];
    const float* ln_g     = (const float*)d_in[9];
    const float* ln_b     = (const float*)d_in[10];
    const int*   mme      = (const int*)d_in[11];
    float* out = (float*)d_out;

    char* ws = (char*)d_ws;
    int*   fi_t = (int*)ws;                                 // 512*256*4 = 512KB
    float* qkw  = (float*)(ws + (512 << 10));               // 512*2048*4 = 4MB
    float* qkb  = (float*)(ws + (512 << 10) + (4 << 20));   // 16KB
    float* aff  = out + AFF_OFF;

    hipLaunchKernelGGL(k_sample_qkw, dim3(NSLOT), dim3(256), 0, stream,
                       curio, mme, slots, ipw, ipb, fi_t, qkw, qkb);
    hipLaunchKernelGGL(k_attn, dim3(NSLOT), dim3(512), 0, stream,
                       features, pos_enc, batch_idx, fi_t, qkw, qkb, slots, ipw, ipb,
                       out_w, out_b, ln_g, ln_b, aff, out);
}

// Round 4
// 132.599 us; speedup vs baseline: 1.2652x; 1.2652x over previous
//
#include <hip/hip_runtime.h>
#include <hip/hip_bf16.h>

#define FEAT 256
#define HEADS 8
#define HD 32
#define POSN 128
#define NEGN 128
#define HWN 16384
#define BN 8
#define NSLOT 512
#define S_TOT 256
#define LN_EPS 1e-5f
#define NBKT 4096
#define AFF_OFF (NSLOT*FEAT)   /* 131072 floats: new_slots first, then affinities */

typedef float f32x4 __attribute__((ext_vector_type(4)));

// ---------------- K1: exact feat_idx sampling + folded qkw -------------------
// One block per slot. Single streaming pass over curio (f32x4 loads); bucket
// ids cached packed in registers so the scatter pass re-reads nothing.
__global__ __launch_bounds__(256) void k_sample_qkw(const float* __restrict__ curio,
                                                    const int* __restrict__ mme_p,
                                                    const float* __restrict__ slots,
                                                    const float* __restrict__ ipw,
                                                    const float* __restrict__ ipb,
                                                    int* __restrict__ fi_t,
                                                    float* __restrict__ qkw,
                                                    float* __restrict__ qkb)
{
    __shared__ uint32_t hist[NBKT];    // 16KB
    __shared__ uint16_t offs[NBKT];    // 8KB
    __shared__ uint16_t sidx[HWN];     // 32KB
    __shared__ uint32_t ssum[256];     // 1KB
    __shared__ float srow[FEAT];       // 1KB
    __shared__ float qrow[FEAT];       // 1KB
    int slot = blockIdx.x, t = threadIdx.x;
    const float* cm = curio + (size_t)slot * HWN;
    const f32x4* cm4 = (const f32x4*)cm;

    for (int i = t; i < NBKT; i += 256) hist[i] = 0;
    __syncthreads();

    // pass 1: vectorized stream + histogram; cache bucket ids in registers
    uint32_t bkA[16], bkB[16];
#pragma unroll
    for (int j = 0; j < 16; j++) {
        f32x4 v = cm4[j * 256 + t];
        int b0 = (int)(v[0] * 4096.0f); b0 = b0 < 0 ? 0 : (b0 > NBKT-1 ? NBKT-1 : b0);
        int b1 = (int)(v[1] * 4096.0f); b1 = b1 < 0 ? 0 : (b1 > NBKT-1 ? NBKT-1 : b1);
        int b2 = (int)(v[2] * 4096.0f); b2 = b2 < 0 ? 0 : (b2 > NBKT-1 ? NBKT-1 : b2);
        int b3 = (int)(v[3] * 4096.0f); b3 = b3 < 0 ? 0 : (b3 > NBKT-1 ? NBKT-1 : b3);
        bkA[j] = (uint32_t)b0 | ((uint32_t)b1 << 16);
        bkB[j] = (uint32_t)b2 | ((uint32_t)b3 << 16);
        atomicAdd(&hist[b0], 1u); atomicAdd(&hist[b1], 1u);
        atomicAdd(&hist[b2], 1u); atomicAdd(&hist[b3], 1u);
    }
    __syncthreads();

    // descending-order exclusive prefix: offs[b] = sum_{b'>b} hist[b']
    uint32_t lsum = 0;
    int base = t * 16;
    for (int j = 0; j < 16; j++) lsum += hist[NBKT-1 - (base + j)];
    ssum[t] = lsum; __syncthreads();
    for (int off = 1; off < 256; off <<= 1) {
        uint32_t v = (t >= off) ? ssum[t - off] : 0u;
        __syncthreads();
        ssum[t] += v;
        __syncthreads();
    }
    uint32_t run = ssum[t] - lsum;
    for (int j = 0; j < 16; j++) {
        int b = NBKT-1 - (base + j);
        offs[b] = (uint16_t)run;
        run += hist[b];
    }
    __syncthreads();
    for (int i = t; i < NBKT; i += 256) hist[i] = 0;
    __syncthreads();

    // pass 2: scatter from register-cached buckets (no curio re-read)
#pragma unroll
    for (int j = 0; j < 16; j++) {
        int idx0 = (j * 256 + t) * 4;
        int b0 = (int)(bkA[j] & 0xFFFFu), b1 = (int)(bkA[j] >> 16);
        int b2 = (int)(bkB[j] & 0xFFFFu), b3 = (int)(bkB[j] >> 16);
        uint32_t p0 = (uint32_t)offs[b0] + atomicAdd(&hist[b0], 1u);
        sidx[p0] = (uint16_t)(idx0 + 0);
        uint32_t p1 = (uint32_t)offs[b1] + atomicAdd(&hist[b1], 1u);
        sidx[p1] = (uint16_t)(idx0 + 1);
        uint32_t p2 = (uint32_t)offs[b2] + atomicAdd(&hist[b2], 1u);
        sidx[p2] = (uint16_t)(idx0 + 2);
        uint32_t p3 = (uint32_t)offs[b3] + atomicAdd(&hist[b3], 1u);
        sidx[p3] = (uint16_t)(idx0 + 3);
    }
    __syncthreads();

    // exact rank selection (argsort of -v, stable: value desc, idx asc)
    int mme = mme_p[0];
    int stride = (HWN - POSN - mme) / NEGN;          // 127 for mme=0
    int r = (t < POSN) ? t : (POSN + stride * (t - POSN));
    int lo = 0, hi = NBKT - 1;
    while (lo < hi) { int mid = (lo + hi) >> 1; if ((int)offs[mid] <= r) hi = mid; else lo = mid + 1; }
    int bkt = lo;
    int start = (int)offs[bkt];
    int cnt   = (int)hist[bkt];
    int rr = r - start;
    int besti = sidx[start + (rr < cnt ? rr : 0)];
    for (int j = 0; j < cnt; j++) {
        int ij = sidx[start + j];
        float vj = cm[ij];
        int rank = 0;
        for (int j2 = 0; j2 < cnt; j2++) {
            int i2 = sidx[start + j2];
            float v2 = cm[i2];
            if (v2 > vj || (v2 == vj && i2 < ij)) rank++;
        }
        if (rank == rr) { besti = ij; break; }
    }
    fi_t[slot * S_TOT + t] = besti;   // fi_t[n][s]

    // ---- folded qkw for this slot ----
    __syncthreads();
    srow[t] = slots[slot * FEAT + t];
    __syncthreads();
    {
        const float* qwrow = ipw + (size_t)t * FEAT;
        float acc = 0.f;
#pragma unroll 8
        for (int f = 0; f < FEAT; f++) acc += srow[f] * qwrow[f];
        const float scaling = 0.17677669529663687f;     // 32^-0.5
        qrow[t] = (acc + ipb[t]) * scaling;
    }
    __syncthreads();
    if (t < HEADS) {
        float s = 0.f;
        for (int d = 0; d < HD; d++) s += qrow[t*HD + d] * ipb[FEAT + t*HD + d];
        qkb[slot * HEADS + t] = s;
    }
    const float* kw = ipw + FEAT * FEAT;
    for (int e = t; e < HEADS * FEAT; e += 256) {
        int h = e >> 8, f = e & 255;
        float s = 0.f;
#pragma unroll
        for (int d = 0; d < HD; d++) s += qrow[h*HD + d] * kw[(h*HD + d) * FEAT + f];
        qkw[(size_t)slot * (HEADS*FEAT) + e] = s;
    }
}

// ---------------- K2: fused affinity + softmax + output ---------------------
// One block per slot, 512 threads (8 waves). Wave w gathers rows p = w + 8*i
// (feat+pos, cacheable loads), computes affinities in registers with a 64-lane
// value-halving butterfly. POS rows (i<16) keep their feat float4 in registers.
// Then softmax, register-cached weighted-feature sum (two-batch 32KB LDS
// combine), V-proj, out-proj, residual+LN. LDS ~50KB -> 2 blocks/CU.
__global__ __launch_bounds__(512, 2) void k_attn(const float* __restrict__ features,
                                                 const float* __restrict__ pos_enc,
                                                 const int* __restrict__ batch_idx,
                                                 const int* __restrict__ fi_t,
                                                 const float* __restrict__ qkw,
                                                 const float* __restrict__ qkb,
                                                 const float* __restrict__ slots,
                                                 const float* __restrict__ ipw,
                                                 const float* __restrict__ ipb,
                                                 const float* __restrict__ out_w,
                                                 const float* __restrict__ out_b,
                                                 const float* __restrict__ ln_g,
                                                 const float* __restrict__ ln_b,
                                                 float* __restrict__ aff_out,
                                                 float* __restrict__ out)
{
    __shared__ int   fi_l[S_TOT];                      // 1KB
    __shared__ float qkb_l[HEADS];
    __shared__ __align__(16) float affP[POSN][8];      // 4KB: aff then attn
    __shared__ f32x4 wfp[4][HEADS][64];                // 32KB per-wave partials
    __shared__ f32x4 wf4[HEADS][64];                   // 8KB combined
    __shared__ float aoh[512];                         // 2KB
    __shared__ __align__(16) float ao_l[FEAT];         // 1KB
    __shared__ float xgh[512];                         // 2KB
    __shared__ float r1[4], r2[4];

    int n = blockIdx.x, t = threadIdx.x, lane = t & 63, w = t >> 6;
    if (t < S_TOT) fi_l[t] = fi_t[n * S_TOT + t];
    if (t < HEADS) qkb_l[t] = qkb[n * HEADS + t];
    int b = batch_idx[n];

    const float* qk = qkw + (size_t)n * (HEADS*FEAT) + 4 * lane;
    f32x4 qw0 = *(const f32x4*)(qk + 0*FEAT);
    f32x4 qw1 = *(const f32x4*)(qk + 1*FEAT);
    f32x4 qw2 = *(const f32x4*)(qk + 2*FEAT);
    f32x4 qw3 = *(const f32x4*)(qk + 3*FEAT);
    f32x4 qw4 = *(const f32x4*)(qk + 4*FEAT);
    f32x4 qw5 = *(const f32x4*)(qk + 5*FEAT);
    f32x4 qw6 = *(const f32x4*)(qk + 6*FEAT);
    f32x4 qw7 = *(const f32x4*)(qk + 7*FEAT);
    __syncthreads();
    float qb = qkb_l[lane & 7];
    int b0 = lane & 1, b1 = (lane >> 1) & 1, b2 = (lane >> 2) & 1;

    auto dorow = [&](int p, f32x4 cf, f32x4 cg) {
        float x0 = cf[0]+cg[0], x1 = cf[1]+cg[1], x2 = cf[2]+cg[2], x3 = cf[3]+cg[3];
        float p0 = x0*qw0[0] + x1*qw0[1] + x2*qw0[2] + x3*qw0[3];
        float p1 = x0*qw1[0] + x1*qw1[1] + x2*qw1[2] + x3*qw1[3];
        float p2 = x0*qw2[0] + x1*qw2[1] + x2*qw2[2] + x3*qw2[3];
        float p3 = x0*qw3[0] + x1*qw3[1] + x2*qw3[2] + x3*qw3[3];
        float p4 = x0*qw4[0] + x1*qw4[1] + x2*qw4[2] + x3*qw4[3];
        float p5 = x0*qw5[0] + x1*qw5[1] + x2*qw5[2] + x3*qw5[3];
        float p6 = x0*qw6[0] + x1*qw6[1] + x2*qw6[2] + x3*qw6[3];
        float p7 = x0*qw7[0] + x1*qw7[1] + x2*qw7[2] + x3*qw7[3];
        float s0 = b0 ? p0 : p1, s1 = b0 ? p2 : p3, s2 = b0 ? p4 : p5, s3 = b0 ? p6 : p7;
        float a0 = (b0 ? p1 : p0) + __shfl_xor(s0, 1);
        float a1 = (b0 ? p3 : p2) + __shfl_xor(s1, 1);
        float a2 = (b0 ? p5 : p4) + __shfl_xor(s2, 1);
        float a3 = (b0 ? p7 : p6) + __shfl_xor(s3, 1);
        float u0 = b1 ? a0 : a1, u1 = b1 ? a2 : a3;
        float c0 = (b1 ? a1 : a0) + __shfl_xor(u0, 2);
        float c1 = (b1 ? a3 : a2) + __shfl_xor(u1, 2);
        float u2 = b2 ? c0 : c1;
        float d = (b2 ? c1 : c0) + __shfl_xor(u2, 4);
        d += __shfl_xor(d, 8);
        d += __shfl_xor(d, 16);
        d += __shfl_xor(d, 32);
        d += qb;
        if (lane < 8) {
            aff_out[(size_t)p * (NSLOT*HEADS) + n*HEADS + lane] = d;
            if (p < POSN) affP[p][lane] = d;
        }
    };

    f32x4 cache[16];
    size_t base0 = ((size_t)fi_l[w] * BN + b) * FEAT + 4 * lane;
    f32x4 f4 = *(const f32x4*)(features + base0);
    f32x4 g4 = *(const f32x4*)(pos_enc + base0);
#pragma unroll
    for (int i = 0; i < 16; i++) {
        f32x4 cf = f4, cg = g4;
        {
            size_t nb = ((size_t)fi_l[w + 8*(i+1)] * BN + b) * FEAT + 4 * lane;
            f4 = *(const f32x4*)(features + nb);
            g4 = *(const f32x4*)(pos_enc + nb);
        }
        cache[i] = cf;
        dorow(w + 8*i, cf, cg);
    }
#pragma unroll 4
    for (int i = 16; i < 32; i++) {
        f32x4 cf = f4, cg = g4;
        if (i < 31) {
            size_t nb = ((size_t)fi_l[w + 8*(i+1)] * BN + b) * FEAT + 4 * lane;
            f4 = *(const f32x4*)(features + nb);
            g4 = *(const f32x4*)(pos_enc + nb);
        }
        dorow(w + 8*i, cf, cg);
    }
    __syncthreads();

    // softmax over p<128 per head (t<256: 32-lane groups)
    if (t < 256) {
        int h = t >> 5, l = t & 31;
        float v0 = affP[l][h], v1 = affP[l+32][h], v2 = affP[l+64][h], v3 = affP[l+96][h];
        float m = fmaxf(fmaxf(v0, v1), fmaxf(v2, v3));
        for (int off = 16; off > 0; off >>= 1) m = fmaxf(m, __shfl_xor(m, off, 32));
        float e0 = expf(v0 - m), e1 = expf(v1 - m), e2 = expf(v2 - m), e3 = expf(v3 - m);
        float s = e0 + e1 + e2 + e3;
        for (int off = 16; off > 0; off >>= 1) s += __shfl_xor(s, off, 32);
        float inv = 1.0f / s;
        affP[l][h] = e0*inv; affP[l+32][h] = e1*inv; affP[l+64][h] = e2*inv; affP[l+96][h] = e3*inv;
    }
    __syncthreads();

    // weighted feature sum from register cache
    {
        f32x4 acc[8];
#pragma unroll
        for (int h = 0; h < 8; h++) acc[h] = (f32x4){0.f,0.f,0.f,0.f};
#pragma unroll
        for (int i = 0; i < 16; i++) {
            int p = w + 8*i;
            const f32x4* ap = (const f32x4*)&affP[p][0];
            f32x4 a03 = ap[0], a47 = ap[1];
            acc[0] += cache[i] * a03[0];
            acc[1] += cache[i] * a03[1];
            acc[2] += cache[i] * a03[2];
            acc[3] += cache[i] * a03[3];
            acc[4] += cache[i] * a47[0];
            acc[5] += cache[i] * a47[1];
            acc[6] += cache[i] * a47[2];
            acc[7] += cache[i] * a47[3];
        }
        // two-batch combine into 32KB of partials
        if (w < 4) {
#pragma unroll
            for (int h = 0; h < 8; h++) wfp[w][h][lane] = acc[h];
        }
        __syncthreads();
        if (w >= 4) {
#pragma unroll
            for (int h = 0; h < 8; h++) wfp[w-4][h][lane] += acc[h];
        }
        __syncthreads();
    }
    {   // combine 4 partials (HEADS*64 = 512 elements, one per thread)
        int h = t >> 6, q2 = t & 63;
        f32x4 s = wfp[0][h][q2] + wfp[1][h][q2] + wfp[2][h][q2] + wfp[3][h][q2];
        wf4[h][q2] = s;
    }
    __syncthreads();

    // V-projection split in half across 512 threads
    {
        int g = t & 255, half = t >> 8;
        const float* vwrow = ipw + (size_t)(2*FEAT + g) * FEAT + half*128;
        const f32x4* wfv = &wf4[g >> 5][half*32];
        float s = 0.f;
#pragma unroll 8
        for (int f4i = 0; f4i < 32; f4i++) {
            f32x4 wv = *(const f32x4*)(vwrow + 4*f4i);
            f32x4 y = wfv[f4i];
            s += wv[0]*y[0] + wv[1]*y[1] + wv[2]*y[2] + wv[3]*y[3];
        }
        aoh[t] = s;
    }
    __syncthreads();
    if (t < 256) ao_l[t] = aoh[t] + aoh[t + 256] + ipb[2*FEAT + t];
    __syncthreads();

    // out-projection split in half
    {
        int g = t & 255, half = t >> 8;
        const float* owrow = out_w + (size_t)g * FEAT + half*128;
        const f32x4* av = (const f32x4*)&ao_l[half*128];
        float s = 0.f;
#pragma unroll 8
        for (int f4i = 0; f4i < 32; f4i++) {
            f32x4 wv = *(const f32x4*)(owrow + 4*f4i);
            f32x4 y = av[f4i];
            s += wv[0]*y[0] + wv[1]*y[1] + wv[2]*y[2] + wv[3]*y[3];
        }
        xgh[t] = s;
    }
    __syncthreads();

    float xg = 0.f;
    if (t < 256) {
        xg = xgh[t] + xgh[t + 256] + out_b[t] + slots[n * FEAT + t];
        float s1 = xg, s2 = xg * xg;
        for (int off = 32; off > 0; off >>= 1) {
            s1 += __shfl_xor(s1, off);
            s2 += __shfl_xor(s2, off);
        }
        if ((t & 63) == 0) { r1[t >> 6] = s1; r2[t >> 6] = s2; }
    }
    __syncthreads();
    if (t < 256) {
        float sum1 = r1[0] + r1[1] + r1[2] + r1[3];
        float sum2 = r2[0] + r2[1] + r2[2] + r2[3];
        float mu  = sum1 * (1.0f / FEAT);
        float var = sum2 * (1.0f / FEAT) - mu * mu;
        float nrm = (xg - mu) * rsqrtf(var + LN_EPS);
        out[n * FEAT + t] = nrm * ln_g[t] + ln_b[t];
    }
}

extern "C" void kernel_launch(void* const* d_in, const int* in_sizes, int n_in,
                              void* d_out, int out_size, void* d_ws, size_t ws_size,
                              hipStream_t stream)
{
    (void)in_sizes; (void)n_in; (void)out_size; (void)ws_size;
    const float* slots    = (const float*)d_in[0];
    const float* features = (const float*)d_in[1];
    const float* pos_enc  = (const float*)d_in[2];
    const float* curio    = (const float*)d_in[3];
    const int*   batch_idx= (const int*)d_in[4];
    const float* ipw      = (const float*)d_in[5];
    const float* ipb      = (const float*)d_in[6];
    const float* out_w    = (const float*)d_in[7];
    const float* out_b    = (const float*)d_in[8];
    const float* ln_g     = (const float*)d_in[9];
    const float* ln_b     = (const float*)d_in[10];
    const int*   mme      = (const int*)d_in[11];
    float* out = (float*)d_out;

    char* ws = (char*)d_ws;
    int*   fi_t = (int*)ws;                                 // 512*256*4 = 512KB
    float* qkw  = (float*)(ws + (512 << 10));               // 512*2048*4 = 4MB
    float* qkb  = (float*)(ws + (512 << 10) + (4 << 20));   // 16KB
    float* aff  = out + AFF_OFF;

    hipLaunchKernelGGL(k_sample_qkw, dim3(NSLOT), dim3(256), 0, stream,
                       curio, mme, slots, ipw, ipb, fi_t, qkw, qkb);
    hipLaunchKernelGGL(k_attn, dim3(NSLOT), dim3(512), 0, stream,
                       features, pos_enc, batch_idx, fi_t, qkw, qkb, slots, ipw, ipb,
                       out_w, out_b, ln_g, ln_b, aff, out);
}